// Round 11
// baseline (277.845 us; speedup 1.0000x reference)
//
#include <hip/hip_runtime.h>

// Segment-sum over sorted ray indices + gather-back, no atomics.
//   d_in[0]: sample_values f32 [n_samples * D]
//   d_in[1]: ray_indices  i32 [n_samples] (sorted, non-decreasing)
//   d_in[2]: n_rays (device scalar, unused -- derived from sizes)
//   d_out  : [n_rays*D] per-ray sums, then [n_samples*D] per-sample gathered sums
//
// Kernel A (bounds): boundary threads write seg_start/seg_end AND fill empty
//   rays with start==end -> no memset pass, no -1 sentinels.
// Kernel B (raysum): one wave per 8 rays, SOFTWARE-PIPELINED: while ray r is
//   being reduced and stored, ray r+1's 3 load windows (96 samples, mean 64 +
//   4 sigma; zero-masked by length) are already in flight. This removes the
//   per-ray ~900-cycle HBM latency exposure that capped R6/R9 at 2.2-2.4 TB/s
//   (loads could not issue until the previous ray's shuffle-reduce, which
//   depends on that ray's loads, had completed). Rays >96 samples take a
//   rare residual loop. Plain stores (NT stores regressed R9; the harness
//   fill kernel proves plain write streams run at 6.8 TB/s).

#define DCH 8
#define RPW 8  // rays per wave

typedef float f32x4 __attribute__((ext_vector_type(4)));

__global__ void __launch_bounds__(256) bounds_kernel(
    const int* __restrict__ rays,
    int* __restrict__ seg_start,
    int* __restrict__ seg_end,
    int n_samples, int n_rays) {
  long i = (long)blockIdx.x * blockDim.x + threadIdx.x;
  if (i >= n_samples) return;
  int r = rays[i];
  if (i == 0) {
    seg_start[r] = 0;
    for (int g = 0; g < r; ++g) { seg_start[g] = 0; seg_end[g] = 0; }
  } else {
    int rp = rays[i - 1];
    if (rp != r) {
      seg_end[rp] = (int)i;
      seg_start[r] = (int)i;
      for (int g = rp + 1; g < r; ++g) { seg_start[g] = (int)i; seg_end[g] = (int)i; }
    }
  }
  if (i == n_samples - 1) {
    seg_end[r] = n_samples;
    for (int g = r + 1; g < n_rays; ++g) { seg_start[g] = n_samples; seg_end[g] = n_samples; }
  }
}

__global__ void __launch_bounds__(256) raysum_kernel(
    const f32x4* __restrict__ vals4,
    const int* __restrict__ seg_start,
    const int* __restrict__ seg_end,
    f32x4* __restrict__ out_ray4,
    f32x4* __restrict__ out_sample4,
    int n_rays) {
  const int wave = blockIdx.x * (blockDim.x >> 6) + (threadIdx.x >> 6);
  const int base = wave * RPW;
  if (base >= n_rays) return;
  const int lane = threadIdx.x & 63;
  const int sl = lane >> 1;  // sample slot within a 32-sample window
  const int h = lane & 1;    // float4 half of the 32B sample

  // Coalesced bounds prefetch for this wave's 8 rays.
  const int ridx = base + (lane & (RPW - 1));
  int rs = 0, re = 0;
  if (ridx < n_rays) {
    rs = seg_start[ridx];
    re = seg_end[ridx];
  }

  const f32x4 zero = {0.f, 0.f, 0.f, 0.f};

  // Prologue: issue ray 0's three windows.
  int s0n = __shfl(rs, 0, 64);
  int s1n = __shfl(re, 0, 64);
  f32x4 n0 = (s0n + sl < s1n) ? vals4[(long)(s0n + sl) * 2 + h] : zero;
  f32x4 n1 = (s0n + 32 + sl < s1n) ? vals4[(long)(s0n + 32 + sl) * 2 + h] : zero;
  f32x4 n2 = (s0n + 64 + sl < s1n) ? vals4[(long)(s0n + 64 + sl) * 2 + h] : zero;

#pragma unroll 1
  for (int r = 0; r < RPW; ++r) {
    if (base + r >= n_rays) break;
    const int s0 = s0n, s1 = s1n;
    f32x4 w0 = n0, w1 = n1, w2 = n2;

    // Issue ray r+1's loads BEFORE consuming ray r's (latency overlap).
    if (r + 1 < RPW) {
      s0n = __shfl(rs, r + 1, 64);
      s1n = __shfl(re, r + 1, 64);
      n0 = (s0n + sl < s1n) ? vals4[(long)(s0n + sl) * 2 + h] : zero;
      n1 = (s0n + 32 + sl < s1n) ? vals4[(long)(s0n + 32 + sl) * 2 + h] : zero;
      n2 = (s0n + 64 + sl < s1n) ? vals4[(long)(s0n + 64 + sl) * 2 + h] : zero;
    }

    f32x4 acc = w0 + w1 + w2;
    // Residual for rays longer than 96 samples (p ~ 3e-5; correctness only).
    for (int j = s0 + 96 + sl; j < s1; j += 32) {
      acc += vals4[(long)j * 2 + h];
    }

    // Reduce across the 32 sample slots (lane bits 1..5); each lane ends with
    // the full ray sum for its float4 half.
#pragma unroll
    for (int off = 2; off <= 32; off <<= 1) {
      acc.x += __shfl_xor(acc.x, off, 64);
      acc.y += __shfl_xor(acc.y, off, 64);
      acc.z += __shfl_xor(acc.z, off, 64);
      acc.w += __shfl_xor(acc.w, off, 64);
    }

    // Per-ray sum: lanes 0 (h=0) and 1 (h=1) hold the two halves.
    if (lane < 2) {
      out_ray4[(long)(base + r) * 2 + lane] = acc;
    }

    // Broadcast the ray sum back over this ray's samples (contiguous 1 KB
    // stores per window).
    for (int j = s0 + sl; j < s1; j += 32) {
      out_sample4[(long)j * 2 + h] = acc;
    }
  }
}

extern "C" void kernel_launch(void* const* d_in, const int* in_sizes, int n_in,
                              void* d_out, int out_size, void* d_ws, size_t ws_size,
                              hipStream_t stream) {
  const float* vals = (const float*)d_in[0];
  const int* rays   = (const int*)d_in[1];

  const int n_samples = in_sizes[1];
  const int d         = in_sizes[0] / n_samples;   // = 8
  const int n_rays    = out_size / d - n_samples;  // = 65536

  float* out_ray    = (float*)d_out;
  float* out_sample = out_ray + (size_t)n_rays * d;

  int* seg_start = (int*)d_ws;
  int* seg_end   = seg_start + n_rays;

  bounds_kernel<<<(int)(((long)n_samples + 255) / 256), 256, 0, stream>>>(
      rays, seg_start, seg_end, n_samples, n_rays);

  // One wave per 8 rays: 8192 waves, 4 waves per 256-thread block.
  const int nwaves = (n_rays + RPW - 1) / RPW;
  const int nblocks = (nwaves + 3) / 4;
  raysum_kernel<<<nblocks, 256, 0, stream>>>(
      reinterpret_cast<const f32x4*>(vals), seg_start, seg_end,
      reinterpret_cast<f32x4*>(out_ray),
      reinterpret_cast<f32x4*>(out_sample), n_rays);
}

// Round 12
// 258.417 us; speedup vs baseline: 1.0752x; 1.0752x over previous
//
#include <hip/hip_runtime.h>

// Segment-sum over sorted ray indices + gather-back, no atomics.
//   d_in[0]: sample_values f32 [n_samples * D]
//   d_in[1]: ray_indices  i32 [n_samples] (sorted, non-decreasing)
//   d_in[2]: n_rays (device scalar, unused -- derived from sizes)
//   d_out  : [n_rays*D] per-ray sums, then [n_samples*D] per-sample gathered sums
//
// Kernel A (bounds): boundary threads write seg_start/seg_end AND fill empty
//   rays with start==end -> no memset pass, no -1 sentinels.
// Kernel B (raysum): one wave per 8 rays, processed as 2 batches of 4 with
//   ALL 24 load windows issued up front (24 KB in flight per wave vs 3 KB in
//   R9/R11) and the 4 shuffle-reduce chains of a batch INTERLEAVED. R11
//   post-mortem: per-ray serialized {load-wait + 5-step dependent ds-pipe
//   reduce (~300-600 cyc) + stores} x 8 = ~780 cyc/ray/wave matched the
//   measured 94 us exactly; depth-1 pipelining didn't break that chain.
//   Batching 4 independent reduces gives ~4x ILP on the ds-pipe latency and
//   the big outstanding-load pool removes the load-wait from the chain.
//   Loads are clamp-addressed + cndmask-zeroed (no exec-mask churn).

#define DCH 8
#define RPW 8   // rays per wave
#define BATCH 4 // rays reduced concurrently

typedef float f32x4 __attribute__((ext_vector_type(4)));

__global__ void __launch_bounds__(256) bounds_kernel(
    const int* __restrict__ rays,
    int* __restrict__ seg_start,
    int* __restrict__ seg_end,
    int n_samples, int n_rays) {
  long i = (long)blockIdx.x * blockDim.x + threadIdx.x;
  if (i >= n_samples) return;
  int r = rays[i];
  if (i == 0) {
    seg_start[r] = 0;
    for (int g = 0; g < r; ++g) { seg_start[g] = 0; seg_end[g] = 0; }
  } else {
    int rp = rays[i - 1];
    if (rp != r) {
      seg_end[rp] = (int)i;
      seg_start[r] = (int)i;
      for (int g = rp + 1; g < r; ++g) { seg_start[g] = (int)i; seg_end[g] = (int)i; }
    }
  }
  if (i == n_samples - 1) {
    seg_end[r] = n_samples;
    for (int g = r + 1; g < n_rays; ++g) { seg_start[g] = n_samples; seg_end[g] = n_samples; }
  }
}

__device__ __forceinline__ f32x4 loadw(const f32x4* __restrict__ vals4,
                                       long j, int s1, int nsm1, int h) {
  long jc = j < (long)nsm1 ? j : (long)nsm1;  // clamp: stay in-bounds
  f32x4 v = vals4[jc * 2 + h];
  f32x4 z = {0.f, 0.f, 0.f, 0.f};
  return (j < (long)s1) ? v : z;  // cndmask after load, no exec churn
}

__global__ void __launch_bounds__(256) raysum_kernel(
    const f32x4* __restrict__ vals4,
    const int* __restrict__ seg_start,
    const int* __restrict__ seg_end,
    f32x4* __restrict__ out_ray4,
    f32x4* __restrict__ out_sample4,
    int n_rays, int n_samples) {
  const int wave = blockIdx.x * (blockDim.x >> 6) + (threadIdx.x >> 6);
  const int base = wave * RPW;
  if (base >= n_rays) return;
  const int lane = threadIdx.x & 63;
  const int sl = lane >> 1;  // sample slot within a 32-sample window
  const int h = lane & 1;    // float4 half of the 32B sample
  const int nsm1 = n_samples - 1;

  // Coalesced bounds fetch for this wave's 8 rays; __shfl(.., const) lowers
  // to v_readlane -> bounds live in SGPRs.
  const int ridx = base + (lane & (RPW - 1));
  int rs = 0, re = 0;
  if (ridx < n_rays) {
    rs = seg_start[ridx];
    re = seg_end[ridx];
  }

  int a0[BATCH], a1[BATCH], b0[BATCH], b1[BATCH];
#pragma unroll
  for (int q = 0; q < BATCH; ++q) {
    a0[q] = __shfl(rs, q, 64);
    a1[q] = __shfl(re, q, 64);
    b0[q] = __shfl(rs, BATCH + q, 64);
    b1[q] = __shfl(re, BATCH + q, 64);
  }

  // Issue ALL 24 window loads (8 rays x 3 windows) before any consumption.
  f32x4 wa[BATCH][3], wb[BATCH][3];
#pragma unroll
  for (int q = 0; q < BATCH; ++q)
#pragma unroll
    for (int k = 0; k < 3; ++k)
      wa[q][k] = loadw(vals4, (long)a0[q] + 32 * k + sl, a1[q], nsm1, h);
#pragma unroll
  for (int q = 0; q < BATCH; ++q)
#pragma unroll
    for (int k = 0; k < 3; ++k)
      wb[q][k] = loadw(vals4, (long)b0[q] + 32 * k + sl, b1[q], nsm1, h);

  // ---- Batch A: rays base+0..3 ----
  {
    f32x4 acc[BATCH];
#pragma unroll
    for (int q = 0; q < BATCH; ++q) acc[q] = wa[q][0] + wa[q][1] + wa[q][2];
    // Residual for rays >96 samples (Poisson tail, ~4 rays total; correctness).
#pragma unroll
    for (int q = 0; q < BATCH; ++q)
      for (long j = (long)a0[q] + 96 + sl; j < a1[q]; j += 32)
        acc[q] += vals4[j * 2 + h];
    // Four INDEPENDENT 5-step reduces, interleaved for ds-pipe ILP.
#pragma unroll
    for (int off = 2; off <= 32; off <<= 1) {
#pragma unroll
      for (int q = 0; q < BATCH; ++q) {
        acc[q].x += __shfl_xor(acc[q].x, off, 64);
        acc[q].y += __shfl_xor(acc[q].y, off, 64);
        acc[q].z += __shfl_xor(acc[q].z, off, 64);
        acc[q].w += __shfl_xor(acc[q].w, off, 64);
      }
    }
#pragma unroll
    for (int q = 0; q < BATCH; ++q)
      if (lane < 2 && base + q < n_rays)
        out_ray4[(long)(base + q) * 2 + lane] = acc[q];
#pragma unroll
    for (int q = 0; q < BATCH; ++q)
      for (long j = (long)a0[q] + sl; j < a1[q]; j += 32)
        out_sample4[j * 2 + h] = acc[q];
  }

  // ---- Batch B: rays base+4..7 ----
  {
    f32x4 acc[BATCH];
#pragma unroll
    for (int q = 0; q < BATCH; ++q) acc[q] = wb[q][0] + wb[q][1] + wb[q][2];
#pragma unroll
    for (int q = 0; q < BATCH; ++q)
      for (long j = (long)b0[q] + 96 + sl; j < b1[q]; j += 32)
        acc[q] += vals4[j * 2 + h];
#pragma unroll
    for (int off = 2; off <= 32; off <<= 1) {
#pragma unroll
      for (int q = 0; q < BATCH; ++q) {
        acc[q].x += __shfl_xor(acc[q].x, off, 64);
        acc[q].y += __shfl_xor(acc[q].y, off, 64);
        acc[q].z += __shfl_xor(acc[q].z, off, 64);
        acc[q].w += __shfl_xor(acc[q].w, off, 64);
      }
    }
#pragma unroll
    for (int q = 0; q < BATCH; ++q)
      if (lane < 2 && base + BATCH + q < n_rays)
        out_ray4[(long)(base + BATCH + q) * 2 + lane] = acc[q];
#pragma unroll
    for (int q = 0; q < BATCH; ++q)
      for (long j = (long)b0[q] + sl; j < b1[q]; j += 32)
        out_sample4[j * 2 + h] = acc[q];
  }
}

extern "C" void kernel_launch(void* const* d_in, const int* in_sizes, int n_in,
                              void* d_out, int out_size, void* d_ws, size_t ws_size,
                              hipStream_t stream) {
  const float* vals = (const float*)d_in[0];
  const int* rays   = (const int*)d_in[1];

  const int n_samples = in_sizes[1];
  const int d         = in_sizes[0] / n_samples;   // = 8
  const int n_rays    = out_size / d - n_samples;  // = 65536

  float* out_ray    = (float*)d_out;
  float* out_sample = out_ray + (size_t)n_rays * d;

  int* seg_start = (int*)d_ws;
  int* seg_end   = seg_start + n_rays;

  bounds_kernel<<<(int)(((long)n_samples + 255) / 256), 256, 0, stream>>>(
      rays, seg_start, seg_end, n_samples, n_rays);

  // One wave per 8 rays: 8192 waves, 4 waves per 256-thread block.
  const int nwaves = (n_rays + RPW - 1) / RPW;
  const int nblocks = (nwaves + 3) / 4;
  raysum_kernel<<<nblocks, 256, 0, stream>>>(
      reinterpret_cast<const f32x4*>(vals), seg_start, seg_end,
      reinterpret_cast<f32x4*>(out_ray),
      reinterpret_cast<f32x4*>(out_sample), n_rays, n_samples);
}